// Round 1
// baseline (34.302 us; speedup 1.0000x reference)
//
#include <hip/hip_runtime.h>

// CTC greedy decode: B=256, T=1024, C=128, blank = C-1 = 127.
// One block per batch row. 1024 threads = 16 waves.
// Phase 1: wave-cooperative argmax over C per timestep (2 timesteps/wave/iter,
//          float4 loads = 16B/lane, fully coalesced 1KB per wave per iter).
// Phase 2: block-parallel collapse-repeats / drop-blank compaction + -1 fill.

constexpr int B = 256;
constexpr int T = 1024;
constexpr int C = 128;
constexpr int BLANK = C - 1;

__global__ __launch_bounds__(1024)
void ctc_greedy_kernel(const float* __restrict__ logits, int* __restrict__ out) {
    const int b    = blockIdx.x;
    const int tid  = threadIdx.x;
    const int lane = tid & 63;
    const int wid  = tid >> 6;          // wave id 0..15

    __shared__ int am[T];               // per-timestep argmax
    __shared__ int wsum[16];            // per-wave keep totals

    const float* row = logits + (size_t)b * T * C;

    // ---------------- Phase 1: argmax per timestep ----------------
    // Lane l covers classes (l&31)*4 .. +3 of timestep t0 + (l>>5).
    const int half  = lane >> 5;        // 0 or 1: which timestep of the pair
    const int cbase = (lane & 31) * 4;  // class base for this lane

    for (int k = 0; k < 32; ++k) {
        const int t0 = 2 * wid + 32 * k;        // even timestep of the pair
        const float4 v = *reinterpret_cast<const float4*>(
            row + (size_t)(t0 + half) * C + cbase);

        // local argmax of 4, first-occurrence tie-break (strict >)
        float best = v.x; int bidx = cbase;
        if (v.y > best) { best = v.y; bidx = cbase + 1; }
        if (v.z > best) { best = v.z; bidx = cbase + 2; }
        if (v.w > best) { best = v.w; bidx = cbase + 3; }

        // butterfly reduce within each 32-lane half (offsets < 32).
        // min-index on equal values => jnp.argmax first-occurrence semantics.
        #pragma unroll
        for (int off = 1; off <= 16; off <<= 1) {
            float ov = __shfl_xor(best, off, 64);
            int   oi = __shfl_xor(bidx, off, 64);
            if (ov > best || (ov == best && oi < bidx)) { best = ov; bidx = oi; }
        }
        if ((lane & 31) == 0) am[t0 + half] = bidx;
    }
    __syncthreads();

    // ---------------- Phase 2: compaction ----------------
    const int t    = tid;
    const int a    = am[t];
    const int prev = (t > 0) ? am[t - 1] : -1;
    const int keep = (a != prev && a != BLANK) ? 1 : 0;

    // wave-inclusive prefix sum of keep
    int scan = keep;
    #pragma unroll
    for (int off = 1; off <= 32; off <<= 1) {
        int n = __shfl_up(scan, off, 64);
        if (lane >= off) scan += n;
    }
    if (lane == 63) wsum[wid] = scan;
    __syncthreads();

    int waveOff = 0, total = 0;
    #pragma unroll
    for (int w = 0; w < 16; ++w) {
        const int s = wsum[w];
        if (w < wid) waveOff += s;
        total += s;
    }

    int* orow = out + (size_t)b * T;
    if (keep) orow[waveOff + scan - 1] = a;   // positions [0, total)
    if (tid >= total) orow[tid] = -1;         // positions [total, T) — disjoint
}

extern "C" void kernel_launch(void* const* d_in, const int* in_sizes, int n_in,
                              void* d_out, int out_size, void* d_ws, size_t ws_size,
                              hipStream_t stream) {
    const float* logits = (const float*)d_in[0];
    int* out = (int*)d_out;
    ctc_greedy_kernel<<<B, 1024, 0, stream>>>(logits, out);
}

// Round 2
// 27.421 us; speedup vs baseline: 1.2510x; 1.2510x over previous
//
#include <hip/hip_runtime.h>

// CTC greedy decode: B=256, T=1024, C=128, blank = C-1 = 127.
//
// Kernel 1 (argmax): grid = B * (T/64) = 4096 blocks, 256 threads (4 waves).
//   Each wave handles 16 timesteps; 4 lanes per timestep; each lane loads
//   8 independent float4 (classes (l&3)*4 + 16*i, i=0..7) => 8 KB in flight
//   per wave, then a local argmax over 32 elems + 2 butterfly shuffle steps.
//   Per-instruction address pattern: 16 segments x 64 B (contiguous per
//   4-lane group) — fully coalesced. argmax -> d_ws as int[B][T].
//
// Kernel 2 (scan): 256 blocks x 1024 threads. Collapse repeats, drop blanks,
//   compact with -1 fill (verified logic from round 1, am read from ws).

constexpr int B = 256;
constexpr int T = 1024;
constexpr int C = 128;
constexpr int BLANK = C - 1;

__global__ __launch_bounds__(256)
void ctc_argmax_kernel(const float* __restrict__ logits, int* __restrict__ am) {
    const int tid  = threadIdx.x;
    const int lane = tid & 63;
    const int wid  = tid >> 6;                 // 0..3
    const int row  = blockIdx.x >> 4;          // batch index
    const int chunk = blockIdx.x & 15;         // 64-timestep chunk

    const int t     = chunk * 64 + wid * 16 + (lane >> 2); // this lane's timestep
    const int csub  = (lane & 3) * 4;                      // class sub-base

    const float* p = logits + ((size_t)row * T + t) * C + csub;

    // 8 independent 16B loads: classes csub + 16*i + {0..3}, ascending in i.
    float4 v[8];
    #pragma unroll
    for (int i = 0; i < 8; ++i)
        v[i] = *reinterpret_cast<const float4*>(p + 16 * i);

    // Local argmax over 32 elems, first-occurrence (strict >), ascending class order.
    float best = v[0].x; int bidx = csub;
    #pragma unroll
    for (int i = 0; i < 8; ++i) {
        const int cb = csub + 16 * i;
        if (i > 0 && v[i].x > best) { best = v[i].x; bidx = cb; }
        if (v[i].y > best) { best = v[i].y; bidx = cb + 1; }
        if (v[i].z > best) { best = v[i].z; bidx = cb + 2; }
        if (v[i].w > best) { best = v[i].w; bidx = cb + 3; }
    }

    // Reduce across the 4 lanes of this timestep (xor 1, 2 stay in-group).
    #pragma unroll
    for (int off = 1; off <= 2; off <<= 1) {
        float ov = __shfl_xor(best, off, 64);
        int   oi = __shfl_xor(bidx, off, 64);
        if (ov > best || (ov == best && oi < bidx)) { best = ov; bidx = oi; }
    }

    if ((lane & 3) == 0) am[(size_t)row * T + t] = bidx;
}

__global__ __launch_bounds__(1024)
void ctc_scan_kernel(const int* __restrict__ am, int* __restrict__ out) {
    const int b    = blockIdx.x;
    const int tid  = threadIdx.x;
    const int lane = tid & 63;
    const int wid  = tid >> 6;          // wave id 0..15

    __shared__ int wsum[16];

    const int* arow = am + (size_t)b * T;
    const int a    = arow[tid];
    const int prev = (tid > 0) ? arow[tid - 1] : -1;
    const int keep = (a != prev && a != BLANK) ? 1 : 0;

    // wave-inclusive prefix sum of keep
    int scan = keep;
    #pragma unroll
    for (int off = 1; off <= 32; off <<= 1) {
        int n = __shfl_up(scan, off, 64);
        if (lane >= off) scan += n;
    }
    if (lane == 63) wsum[wid] = scan;
    __syncthreads();

    int waveOff = 0, total = 0;
    #pragma unroll
    for (int w = 0; w < 16; ++w) {
        const int s = wsum[w];
        if (w < wid) waveOff += s;
        total += s;
    }

    int* orow = out + (size_t)b * T;
    if (keep) orow[waveOff + scan - 1] = a;   // positions [0, total)
    if (tid >= total) orow[tid] = -1;         // positions [total, T) — disjoint
}

extern "C" void kernel_launch(void* const* d_in, const int* in_sizes, int n_in,
                              void* d_out, int out_size, void* d_ws, size_t ws_size,
                              hipStream_t stream) {
    const float* logits = (const float*)d_in[0];
    int* out = (int*)d_out;
    int* am  = (int*)d_ws;                       // B*T*4 = 1 MiB scratch

    ctc_argmax_kernel<<<B * (T / 64), 256, 0, stream>>>(logits, am);
    ctc_scan_kernel<<<B, 1024, 0, stream>>>(am, out);
}

// Round 3
// 26.573 us; speedup vs baseline: 1.2909x; 1.0319x over previous
//
#include <hip/hip_runtime.h>

// CTC greedy decode: B=256, T=1024, C=128, blank = C-1 = 127. Fused single kernel.
//
// One block per batch row, 1024 threads = 16 waves (4 waves/SIMD via
// __launch_bounds__(1024,4), VGPR <= 128).
//
// Phase 1 (argmax, 4 iterations): 4 lanes per timestep, each lane issues
//   8 independent float4 loads (classes (tid&3)*4 + 16*i) => 8 KB in flight
//   per wave; local argmax over 32 elems (first-occurrence), 2-step
//   __shfl_xor reduce across the 4-lane group, result -> LDS am[t].
//   Iterations are independent -> compiler software-pipelines the loads.
//
// Phase 2 (compaction, verified in rounds 1-2): collapse repeats, drop
//   blanks, block-wide prefix scan, scatter kept tokens, -1 fill.

constexpr int B = 256;
constexpr int T = 1024;
constexpr int C = 128;
constexpr int BLANK = C - 1;

__global__ __launch_bounds__(1024, 4)
void ctc_fused_kernel(const float* __restrict__ logits, int* __restrict__ out) {
    const int b    = blockIdx.x;
    const int tid  = threadIdx.x;
    const int lane = tid & 63;
    const int wid  = tid >> 6;          // wave id 0..15

    __shared__ int am[T];
    __shared__ int wsum[16];

    const float* row = logits + (size_t)b * T * C;

    // ---------------- Phase 1: argmax per timestep ----------------
    const int csub = (tid & 3) * 4;     // class sub-base for this lane

    #pragma unroll
    for (int k = 0; k < 4; ++k) {
        const int t = k * 256 + (tid >> 2);
        const float* p = row + (size_t)t * C + csub;

        // 8 independent 16B loads: classes csub + 16*i + {0..3}.
        float4 v[8];
        #pragma unroll
        for (int i = 0; i < 8; ++i)
            v[i] = *reinterpret_cast<const float4*>(p + 16 * i);

        // Local argmax over 32 elems, first-occurrence (strict >), ascending order.
        float best = v[0].x; int bidx = csub;
        #pragma unroll
        for (int i = 0; i < 8; ++i) {
            const int cb = csub + 16 * i;
            if (i > 0 && v[i].x > best) { best = v[i].x; bidx = cb; }
            if (v[i].y > best) { best = v[i].y; bidx = cb + 1; }
            if (v[i].z > best) { best = v[i].z; bidx = cb + 2; }
            if (v[i].w > best) { best = v[i].w; bidx = cb + 3; }
        }

        // Reduce across the 4 lanes of this timestep (xor 1,2 stay in-group).
        #pragma unroll
        for (int off = 1; off <= 2; off <<= 1) {
            float ov = __shfl_xor(best, off, 64);
            int   oi = __shfl_xor(bidx, off, 64);
            if (ov > best || (ov == best && oi < bidx)) { best = ov; bidx = oi; }
        }

        if ((tid & 3) == 0) am[t] = bidx;
    }
    __syncthreads();

    // ---------------- Phase 2: compaction ----------------
    const int a    = am[tid];
    const int prev = (tid > 0) ? am[tid - 1] : -1;
    const int keep = (a != prev && a != BLANK) ? 1 : 0;

    // wave-inclusive prefix sum of keep
    int scan = keep;
    #pragma unroll
    for (int off = 1; off <= 32; off <<= 1) {
        int n = __shfl_up(scan, off, 64);
        if (lane >= off) scan += n;
    }
    if (lane == 63) wsum[wid] = scan;
    __syncthreads();

    int waveOff = 0, total = 0;
    #pragma unroll
    for (int w = 0; w < 16; ++w) {
        const int s = wsum[w];
        if (w < wid) waveOff += s;
        total += s;
    }

    int* orow = out + (size_t)b * T;
    if (keep) orow[waveOff + scan - 1] = a;   // positions [0, total)
    if (tid >= total) orow[tid] = -1;         // positions [total, T) — disjoint
}

extern "C" void kernel_launch(void* const* d_in, const int* in_sizes, int n_in,
                              void* d_out, int out_size, void* d_ws, size_t ws_size,
                              hipStream_t stream) {
    const float* logits = (const float*)d_in[0];
    int* out = (int*)d_out;
    ctc_fused_kernel<<<B, 1024, 0, stream>>>(logits, out);
}

// Round 4
// 26.408 us; speedup vs baseline: 1.2990x; 1.0063x over previous
//
#include <hip/hip_runtime.h>

// CTC greedy decode: B=256, T=1024, C=128, blank = C-1 = 127. Fused single kernel.
//
// One block per batch row, 1024 threads = 16 waves.
//
// Phase 1 (argmax, 8 sweeps of 128 timesteps, double-buffered):
//   8 lanes per timestep; lane g=tid&7 loads 4 float4 at byte offsets
//   g*16 + 128*i (i=0..3) => each wave instruction reads 8 FULL aligned
//   128B lines (1KB, no partial lines). Sweep s+1's loads are issued
//   before consuming sweep s (explicit 2-deep pipeline, 8KB/wave in
//   flight, 32 data VGPRs). Local argmax over 16 elems (first-occurrence,
//   ascending class order), 3-step __shfl_xor reduce in the 8-lane group
//   (min-index tie-break), result -> LDS am[t].
//
// Phase 2 (compaction, verified rounds 1-3): collapse repeats, drop
//   blanks, block-wide prefix scan, scatter kept tokens, -1 fill.

constexpr int B = 256;
constexpr int T = 1024;
constexpr int C = 128;
constexpr int BLANK = C - 1;
constexpr int SWEEPS = T / 128;      // 8

__global__ __launch_bounds__(1024, 4)
void ctc_fused_kernel(const float* __restrict__ logits, int* __restrict__ out) {
    const int b    = blockIdx.x;
    const int tid  = threadIdx.x;
    const int lane = tid & 63;
    const int wid  = tid >> 6;          // wave id 0..15

    __shared__ int am[T];
    __shared__ int wsum[16];

    const float* row = logits + (size_t)b * T * C;

    // ---------------- Phase 1: argmax per timestep ----------------
    const int g     = tid & 7;          // lane within 8-lane group
    const int tsub  = tid >> 3;         // group id: timestep within sweep (0..127)
    const int csub  = g * 4;            // class base: csub + 32*i, i=0..3

    float4 buf[2][4];
    {   // prologue: sweep 0
        const float* p = row + (size_t)tsub * C + csub;
        #pragma unroll
        for (int i = 0; i < 4; ++i)
            buf[0][i] = *reinterpret_cast<const float4*>(p + 32 * i);
    }

    #pragma unroll
    for (int s = 0; s < SWEEPS; ++s) {
        if (s + 1 < SWEEPS) {           // issue next sweep's loads first
            const float* p = row + (size_t)((s + 1) * 128 + tsub) * C + csub;
            #pragma unroll
            for (int i = 0; i < 4; ++i)
                buf[(s + 1) & 1][i] = *reinterpret_cast<const float4*>(p + 32 * i);
        }

        // consume sweep s: local argmax over 16 elems, first-occurrence.
        const float4* v = buf[s & 1];
        float best = v[0].x; int bidx = csub;
        #pragma unroll
        for (int i = 0; i < 4; ++i) {
            const int cb = csub + 32 * i;
            if (i > 0 && v[i].x > best) { best = v[i].x; bidx = cb; }
            if (v[i].y > best) { best = v[i].y; bidx = cb + 1; }
            if (v[i].z > best) { best = v[i].z; bidx = cb + 2; }
            if (v[i].w > best) { best = v[i].w; bidx = cb + 3; }
        }

        // reduce across the 8 lanes of this timestep (xor 1,2,4 stay in-group).
        #pragma unroll
        for (int off = 1; off <= 4; off <<= 1) {
            float ov = __shfl_xor(best, off, 64);
            int   oi = __shfl_xor(bidx, off, 64);
            if (ov > best || (ov == best && oi < bidx)) { best = ov; bidx = oi; }
        }

        if (g == 0) am[s * 128 + tsub] = bidx;
    }
    __syncthreads();

    // ---------------- Phase 2: compaction ----------------
    const int a    = am[tid];
    const int prev = (tid > 0) ? am[tid - 1] : -1;
    const int keep = (a != prev && a != BLANK) ? 1 : 0;

    // wave-inclusive prefix sum of keep
    int scan = keep;
    #pragma unroll
    for (int off = 1; off <= 32; off <<= 1) {
        int n = __shfl_up(scan, off, 64);
        if (lane >= off) scan += n;
    }
    if (lane == 63) wsum[wid] = scan;
    __syncthreads();

    int waveOff = 0, total = 0;
    #pragma unroll
    for (int w = 0; w < 16; ++w) {
        const int s = wsum[w];
        if (w < wid) waveOff += s;
        total += s;
    }

    int* orow = out + (size_t)b * T;
    if (keep) orow[waveOff + scan - 1] = a;   // positions [0, total)
    if (tid >= total) orow[tid] = -1;         // positions [total, T) — disjoint
}

extern "C" void kernel_launch(void* const* d_in, const int* in_sizes, int n_in,
                              void* d_out, int out_size, void* d_ws, size_t ws_size,
                              hipStream_t stream) {
    const float* logits = (const float*)d_in[0];
    int* out = (int*)d_out;
    ctc_fused_kernel<<<B, 1024, 0, stream>>>(logits, out);
}